// Round 2
// baseline (607.432 us; speedup 1.0000x reference)
//
#include <hip/hip_runtime.h>
#include <hip/hip_bf16.h>

// Sizes (fixed by the problem)
#define NH   128        // hidden channels H
#define NR   6          // radial
#define NCOL 390        // 3H + 2*SH
#define TILE_E 128      // edges per tile (one block-iteration)
#define LDK  136        // padded LDS row stride (bf16 elems): 128 + 8
#define NBLK 512        // persistent blocks: 2 per CU

typedef __attribute__((ext_vector_type(8))) short bf16x8;   // 8 bf16 in 4 VGPRs
typedef __attribute__((ext_vector_type(4))) float f32x4;

__device__ __forceinline__ float fast_silu(float v) {
    // v * rcp(1 + exp(-v)) : ~5 VALU ops vs ~14 for exact-division silu.
    return v * __builtin_amdgcn_rcpf(1.0f + __expf(-v));
}

// ---------------------------------------------------------------------------
// Single prep kernel (one launch instead of two).
// Blocks 0..189: node tables. side = b&1, a = b>>1. The 3 spin classes share
// one 128-length dot product (3x less work than the old per-row version).
//  Ci[a*3+sc][n] = emb_w[a]·lin_w[n,0:128]   + S[sc]·lin_w[n,128:131] + lin_b[n]
//  Cj[a*3+sc][n] = emb_w[a]·lin_w[n,131:259] + S[sc]·lin_w[n,259:262]
// Blocks 190..317: bf16 copy of lin_w[:, 262:390] -> Wb, row-major [n][k].
// grid = 318, block = 128.
// ---------------------------------------------------------------------------
__global__ void prep_all(const float* __restrict__ emb_w,
                         const float* __restrict__ spin_w,
                         const float* __restrict__ spin_b,
                         const float* __restrict__ lin_w,
                         const float* __restrict__ lin_b,
                         float* __restrict__ Ci, float* __restrict__ Cj,
                         __hip_bfloat16* __restrict__ Wb) {
    int b = blockIdx.x;
    int tid = threadIdx.x;                       // 0..127
    if (b >= 190) {
        int idx = (b - 190) * 128 + tid;         // 0..16383
        int n = idx >> 7, k = idx & 127;
        Wb[idx] = __float2bfloat16(lin_w[(size_t)n * NCOL + 262 + k]);
        return;
    }
    int side = b & 1;                            // 0 = i, 1 = j
    int a    = b >> 1;                           // 0..94
    int n    = tid;
    const int col0 = side ? 131 : 0;
    const int cols = side ? 259 : 128;
    const float* wrow = lin_w + (size_t)n * NCOL;
    const float* ew   = emb_w + a * NH;
    float dot = side ? 0.0f : lin_b[n];
    #pragma unroll 8
    for (int k = 0; k < NH; ++k)
        dot += ew[k] * wrow[col0 + k];
    float* dst = (side ? Cj : Ci) + (size_t)(a * 3) * NH + n;
    #pragma unroll
    for (int sc = 0; sc < 3; ++sc) {
        float acc = dot;
        #pragma unroll
        for (int c = 0; c < 3; ++c)
            acc += (spin_w[c * 3 + sc] + spin_b[c]) * wrow[cols + c];
        dst[(size_t)sc * NH] = acc;
    }
}

// ---------------------------------------------------------------------------
// Main fused kernel: persistent blocks, 128 edges/tile, 512 threads (8 waves).
//   - W staged into LDS ONCE per block.
//   - rbf rows are WAVE-UNIFORM in the r-phase -> read via scalar loads
//     (readfirstlane-derived pointer), not LDS broadcasts. rbf_lds removed;
//     2 barriers/tile instead of 3.
//   - ci/cj indices prefetched one tile ahead into registers.
// LDS: 34816(W) + 34816(r) + 1024(idx) = 70656 B -> 2 blocks/CU, 16 waves/CU.
// ---------------------------------------------------------------------------
__global__ __launch_bounds__(512, 4) void fused_main(
        const int*   __restrict__ x,   const int* __restrict__ s,
        const float* __restrict__ rbf,
        const int*   __restrict__ gi,  const int* __restrict__ gj,
        const float* __restrict__ rbf_w, const float* __restrict__ rbf_b,
        const float* __restrict__ Ci,  const float* __restrict__ Cj,
        const __hip_bfloat16* __restrict__ Wb,
        float* __restrict__ out, int E, int ntiles) {
    __shared__ __align__(16) __hip_bfloat16 w_lds[NH * LDK];
    __shared__ __align__(16) __hip_bfloat16 r_lds[TILE_E * LDK];
    __shared__ int ci_lds[TILE_E], cj_lds[TILE_E];

    const int tid = threadIdx.x;

    // ---- register-staged indices (prefetch target) ----
    int sci = 0, scj = 0;
    auto load_idx = [&](int tt) {
        const int en0 = tt * TILE_E;
        if (tid >= 384) {                      // 128 threads: i-side class
            int e = en0 + (tid - 384); if (e >= E) e = E - 1;
            int ii = gi[e];
            sci = x[ii] * 3 + s[ii];
        }
        if (tid < 128) {                       // 128 threads: j-side class
            int e = en0 + tid; if (e >= E) e = E - 1;
            int jj = gj[e];
            scj = x[jj] * 3 + s[jj];
        }
    };

    const int t0 = blockIdx.x;
    const int gstride = gridDim.x;
    load_idx(t0);

    // ---- stage W once: 2048 x 16B chunks by 512 threads ----
    {
        const uint4* src = (const uint4*)Wb;            // 8 bf16 per chunk
        #pragma unroll
        for (int it = 0; it < 4; ++it) {
            int l = it * 512 + tid;                     // 0..2047
            uint4 v = src[l];
            *(uint4*)&w_lds[(l >> 4) * LDK + (l & 15) * 8] = v;
        }
    }

    // ---- loop-invariant rbf weights: k fixed per thread ----
    const int kk = tid & 127;
    // wave-uniform row-group id (hi = tid>>7 is constant within a wave)
    const int hiu = __builtin_amdgcn_readfirstlane(tid >> 7);   // 0..3
    const float w0 = rbf_w[kk * NR + 0], w1 = rbf_w[kk * NR + 1], w2 = rbf_w[kk * NR + 2];
    const float w3 = rbf_w[kk * NR + 3], w4 = rbf_w[kk * NR + 4], w5 = rbf_w[kk * NR + 5];
    const float bb = rbf_b[kk];

    // ---- wave decomposition for MFMA phase ----
    const int wave   = tid >> 6;              // 0..7, each owns 16 edges
    const int lane   = tid & 63;
    const int lane15 = lane & 15;
    const int quad   = lane >> 4;
    const int e_sub  = wave * 16;
    const int e_row  = e_sub + quad * 4;      // D row base; +reg

    for (int t = t0; t < ntiles; t += gstride) {
        const int e0t = t * TILE_E;
        __syncthreads();      // (a) prev tile's LDS consumers done
        // ---- commit staged indices ----
        if (tid >= 384) ci_lds[tid - 384] = sci;
        if (tid < 128)  cj_lds[tid] = scj;

        // ---- r = silu(rbf @ rbf_w^T + rbf_b) -> bf16 r_lds ----
        // each wave covers rows hiu*32 .. hiu*32+31; rbf row is wave-uniform
        // -> scalar loads (s_load), zero LDS-read traffic. depth-1 pipelined.
        {
            const int egBase = e0t + hiu * 32;
            int eg0 = egBase; if (eg0 > E - 1) eg0 = E - 1;
            const float* rp = rbf + (size_t)eg0 * NR;
            float c0 = rp[0], c1 = rp[1], c2 = rp[2], c3 = rp[3], c4 = rp[4], c5 = rp[5];
            #pragma unroll 4
            for (int it = 0; it < 32; ++it) {
                int egn = egBase + it + 1; if (egn > E - 1) egn = E - 1;
                const float* rn = rbf + (size_t)egn * NR;
                float n0 = rn[0], n1 = rn[1], n2 = rn[2], n3 = rn[3], n4 = rn[4], n5 = rn[5];
                float a = bb + c0 * w0 + c1 * w1 + c2 * w2
                             + c3 * w3 + c4 * w4 + c5 * w5;
                r_lds[(hiu * 32 + it) * LDK + kk] = __float2bfloat16(fast_silu(a));
                c0 = n0; c1 = n1; c2 = n2; c3 = n3; c4 = n4; c5 = n5;
            }
        }
        __syncthreads();      // (b) r_lds + idx visible

        // ---- A fragments + hoisted row base pointers ----
        bf16x8 afrag[4];
        #pragma unroll
        for (int kt = 0; kt < 4; ++kt)
            afrag[kt] = *(const bf16x8*)&r_lds[(e_sub + lane15) * LDK + kt * 32 + quad * 8];

        const float* cip[4]; const float* cjp[4]; float* op[4];
        #pragma unroll
        for (int reg = 0; reg < 4; ++reg) {
            cip[reg] = Ci + ci_lds[e_row + reg] * NH + lane15;
            cjp[reg] = Cj + cj_lds[e_row + reg] * NH + lane15;
            op[reg]  = out + (size_t)(e0t + e_row + reg) * NH + lane15;
        }
        const bool tail = (e0t + TILE_E > E);

        // ---- prefetch next tile's indices (hides under epilogue) ----
        int tn = t + gstride;
        if (tn < ntiles) load_idx(tn);

        // ---- MFMA + epilogue: gathers/stores use immediate offsets only ----
        #pragma unroll
        for (int nt = 0; nt < 8; ++nt) {
            f32x4 acc = {0.f, 0.f, 0.f, 0.f};
            #pragma unroll
            for (int kt = 0; kt < 4; ++kt) {
                bf16x8 bfrag = *(const bf16x8*)&w_lds[(nt * 16 + lane15) * LDK + kt * 32 + quad * 8];
                acc = __builtin_amdgcn_mfma_f32_16x16x32_bf16(afrag[kt], bfrag, acc, 0, 0, 0);
            }
            #pragma unroll
            for (int reg = 0; reg < 4; ++reg) {
                float base = cip[reg][nt * 16] + cjp[reg][nt * 16];
                float v = acc[reg] + base;
                float sv = fast_silu(v);
                if (!tail || (e0t + e_row + reg < E))
                    __builtin_nontemporal_store(sv, op[reg] + nt * 16);
            }
        }
    }
}

// ---------------------------------------------------------------------------
extern "C" void kernel_launch(void* const* d_in, const int* in_sizes, int n_in,
                              void* d_out, int out_size, void* d_ws, size_t ws_size,
                              hipStream_t stream) {
    const int*   x      = (const int*)  d_in[0];
    const int*   s      = (const int*)  d_in[1];
    const float* rbf    = (const float*)d_in[2];
    const int*   gi     = (const int*)  d_in[3];
    const int*   gj     = (const int*)  d_in[4];
    const float* emb_w  = (const float*)d_in[5];
    const float* spin_w = (const float*)d_in[6];
    const float* spin_b = (const float*)d_in[7];
    const float* rbf_w  = (const float*)d_in[8];
    const float* rbf_b  = (const float*)d_in[9];
    const float* lin_w  = (const float*)d_in[10];
    const float* lin_b  = (const float*)d_in[11];
    const int E = in_sizes[3];

    float* Ci = (float*)d_ws;                         // 285*128 f32
    float* Cj = Ci + 285 * NH;                        // 285*128 f32
    __hip_bfloat16* Wb = (__hip_bfloat16*)(Cj + 285 * NH);  // 128*128 bf16

    prep_all<<<318, 128, 0, stream>>>(emb_w, spin_w, spin_b, lin_w, lin_b, Ci, Cj, Wb);

    int ntiles = (E + TILE_E - 1) / TILE_E;
    int nblk = ntiles < NBLK ? ntiles : NBLK;
    fused_main<<<nblk, 512, 0, stream>>>(x, s, rbf, gi, gj, rbf_w, rbf_b,
                                         Ci, Cj, Wb, (float*)d_out, E, ntiles);
}

// Round 4
// 563.812 us; speedup vs baseline: 1.0774x; 1.0774x over previous
//
#include <hip/hip_runtime.h>
#include <hip/hip_bf16.h>

// Sizes (fixed by the problem)
#define NH   128        // hidden channels H
#define NR   6          // radial
#define NCOL 390        // 3H + 2*SH
#define TILE_E 128      // edges per tile (one block-iteration)
#define LDK  136        // padded LDS row stride (bf16 elems): 128 + 8
#define NBLK 512        // persistent blocks: 2 per CU

typedef __attribute__((ext_vector_type(8))) short bf16x8;   // 8 bf16 in 4 VGPRs
typedef __attribute__((ext_vector_type(4))) float f32x4;

__device__ __forceinline__ float fast_silu(float v) {
    // v * rcp(1 + exp(-v)) : ~5 VALU ops vs ~14 for exact-division silu.
    return v * __builtin_amdgcn_rcpf(1.0f + __expf(-v));
}

// ---------------------------------------------------------------------------
// Single prep kernel.
// Blocks 0..189: node tables (side = b&1, a = b>>1); 3 spin classes share one
// 128-length dot product.
// Blocks 190..317: bf16 copy of lin_w[:, 262:390] -> Wb, row-major [n][k].
// ---------------------------------------------------------------------------
__global__ void prep_all(const float* __restrict__ emb_w,
                         const float* __restrict__ spin_w,
                         const float* __restrict__ spin_b,
                         const float* __restrict__ lin_w,
                         const float* __restrict__ lin_b,
                         float* __restrict__ Ci, float* __restrict__ Cj,
                         __hip_bfloat16* __restrict__ Wb) {
    int b = blockIdx.x;
    int tid = threadIdx.x;                       // 0..127
    if (b >= 190) {
        int idx = (b - 190) * 128 + tid;         // 0..16383
        int n = idx >> 7, k = idx & 127;
        Wb[idx] = __float2bfloat16(lin_w[(size_t)n * NCOL + 262 + k]);
        return;
    }
    int side = b & 1;                            // 0 = i, 1 = j
    int a    = b >> 1;                           // 0..94
    int n    = tid;
    const int col0 = side ? 131 : 0;
    const int cols = side ? 259 : 128;
    const float* wrow = lin_w + (size_t)n * NCOL;
    const float* ew   = emb_w + a * NH;
    float dot = side ? 0.0f : lin_b[n];
    #pragma unroll 8
    for (int k = 0; k < NH; ++k)
        dot += ew[k] * wrow[col0 + k];
    float* dst = (side ? Cj : Ci) + (size_t)(a * 3) * NH + n;
    #pragma unroll
    for (int sc = 0; sc < 3; ++sc) {
        float acc = dot;
        #pragma unroll
        for (int c = 0; c < 3; ++c)
            acc += (spin_w[c * 3 + sc] + spin_b[c]) * wrow[cols + c];
        dst[(size_t)sc * NH] = acc;
    }
}

// ---------------------------------------------------------------------------
// Main fused kernel: persistent blocks, 128 edges/tile, 512 threads (8 waves).
// r-phase mapping: thread owns 8 k-channels x 4 edges (kgrp=tid&15,
// egrp=tid>>4). The 16 threads of a lane-quad share one contiguous 16B-aligned
// 96B rbf block -> 6 coalesced dwordx4 global loads, no LDS broadcasts, no
// scalar loads (R2's s_load/ds lgkmcnt mixing serialized — reverted).
// Per-k weights (8x6 + 8 bias = 56 f32) live in registers, loaded once.
// r writes: 4 x ds_write_b128 per thread (8 contiguous bf16 per edge).
// LDS: 34816(W) + 34816(r) + 1024(idx) = 70656 B -> 2 blocks/CU, 16 waves/CU.
// ---------------------------------------------------------------------------
__global__ __launch_bounds__(512, 4) void fused_main(
        const int*   __restrict__ x,   const int* __restrict__ s,
        const float* __restrict__ rbf,
        const int*   __restrict__ gi,  const int* __restrict__ gj,
        const float* __restrict__ rbf_w, const float* __restrict__ rbf_b,
        const float* __restrict__ Ci,  const float* __restrict__ Cj,
        const __hip_bfloat16* __restrict__ Wb,
        float* __restrict__ out, int E, int ntiles) {
    __shared__ __align__(16) __hip_bfloat16 w_lds[NH * LDK];
    __shared__ __align__(16) __hip_bfloat16 r_lds[TILE_E * LDK];
    __shared__ int ci_lds[TILE_E], cj_lds[TILE_E];

    const int tid = threadIdx.x;

    // ---- register-staged indices (prefetch target) ----
    int sci = 0, scj = 0;
    auto load_idx = [&](int tt) {
        const int en0 = tt * TILE_E;
        if (tid >= 384) {                      // 128 threads: i-side class
            int e = en0 + (tid - 384); if (e >= E) e = E - 1;
            int ii = gi[e];
            sci = x[ii] * 3 + s[ii];
        }
        if (tid < 128) {                       // 128 threads: j-side class
            int e = en0 + tid; if (e >= E) e = E - 1;
            int jj = gj[e];
            scj = x[jj] * 3 + s[jj];
        }
    };

    const int t0 = blockIdx.x;
    const int gstride = gridDim.x;
    load_idx(t0);

    // ---- stage W once: 2048 x 16B chunks by 512 threads ----
    {
        const uint4* src = (const uint4*)Wb;            // 8 bf16 per chunk
        #pragma unroll
        for (int it = 0; it < 4; ++it) {
            int l = it * 512 + tid;                     // 0..2047
            uint4 v = src[l];
            *(uint4*)&w_lds[(l >> 4) * LDK + (l & 15) * 8] = v;
        }
    }

    // ---- r-phase mapping + register-resident weights ----
    const int kgrp = tid & 15;                // k-base = kgrp*8
    const int egrp = tid >> 4;                // 0..31 -> edges egrp*4..+3
    float wr[8][6];                           // fully unrolled -> registers
    float br[8];
    #pragma unroll
    for (int j = 0; j < 8; ++j) {
        int k = kgrp * 8 + j;
        #pragma unroll
        for (int i = 0; i < 6; ++i) wr[j][i] = rbf_w[k * NR + i];
        br[j] = rbf_b[k];
    }

    // ---- wave decomposition for MFMA phase ----
    const int wave   = tid >> 6;              // 0..7, each owns 16 edges
    const int lane   = tid & 63;
    const int lane15 = lane & 15;
    const int quad   = lane >> 4;
    const int e_sub  = wave * 16;
    const int e_row  = e_sub + quad * 4;      // D row base; +reg

    for (int t = t0; t < ntiles; t += gstride) {
        const int e0t = t * TILE_E;
        __syncthreads();      // (a) prev tile's LDS consumers done
        // ---- commit staged indices ----
        if (tid >= 384) ci_lds[tid - 384] = sci;
        if (tid < 128)  cj_lds[tid] = scj;

        // ---- r = silu(rbf @ rbf_w^T + rbf_b) -> bf16 r_lds ----
        {
            const int e4 = e0t + egrp * 4;
            float c[4][6];
            if (e4 + 4 <= E) {
                // 96B contiguous, 16B-aligned (e4 % 4 == 0 -> 96*g byte base)
                const float4* q = (const float4*)(rbf + (size_t)e4 * NR);
                float4 q0 = q[0], q1 = q[1], q2 = q[2], q3 = q[3], q4 = q[4], q5 = q[5];
                c[0][0]=q0.x; c[0][1]=q0.y; c[0][2]=q0.z; c[0][3]=q0.w; c[0][4]=q1.x; c[0][5]=q1.y;
                c[1][0]=q1.z; c[1][1]=q1.w; c[1][2]=q2.x; c[1][3]=q2.y; c[1][4]=q2.z; c[1][5]=q2.w;
                c[2][0]=q3.x; c[2][1]=q3.y; c[2][2]=q3.z; c[2][3]=q3.w; c[2][4]=q4.x; c[2][5]=q4.y;
                c[3][0]=q4.z; c[3][1]=q4.w; c[3][2]=q5.x; c[3][3]=q5.y; c[3][4]=q5.z; c[3][5]=q5.w;
            } else {                           // tail tile: clamped per-row
                #pragma unroll
                for (int r = 0; r < 4; ++r) {
                    int er = e4 + r; if (er > E - 1) er = E - 1;
                    const float* rp = rbf + (size_t)er * NR;
                    #pragma unroll
                    for (int i = 0; i < 6; ++i) c[r][i] = rp[i];
                }
            }
            #pragma unroll
            for (int r = 0; r < 4; ++r) {
                bf16x8 pk;
                #pragma unroll
                for (int j = 0; j < 8; ++j) {
                    float a = br[j] + c[r][0] * wr[j][0] + c[r][1] * wr[j][1]
                                    + c[r][2] * wr[j][2] + c[r][3] * wr[j][3]
                                    + c[r][4] * wr[j][4] + c[r][5] * wr[j][5];
                    __hip_bfloat16 h = __float2bfloat16(fast_silu(a));
                    pk[j] = *(short*)&h;
                }
                *(bf16x8*)&r_lds[(egrp * 4 + r) * LDK + kgrp * 8] = pk;
            }
        }
        __syncthreads();      // (b) r_lds + idx visible

        // ---- A fragments + hoisted row base pointers ----
        bf16x8 afrag[4];
        #pragma unroll
        for (int kt = 0; kt < 4; ++kt)
            afrag[kt] = *(const bf16x8*)&r_lds[(e_sub + lane15) * LDK + kt * 32 + quad * 8];

        const float* cip[4]; const float* cjp[4]; float* op[4];
        #pragma unroll
        for (int reg = 0; reg < 4; ++reg) {
            cip[reg] = Ci + ci_lds[e_row + reg] * NH + lane15;
            cjp[reg] = Cj + cj_lds[e_row + reg] * NH + lane15;
            op[reg]  = out + (size_t)(e0t + e_row + reg) * NH + lane15;
        }
        const bool tail = (e0t + TILE_E > E);

        // ---- prefetch next tile's indices (hides under epilogue) ----
        int tn = t + gstride;
        if (tn < ntiles) load_idx(tn);

        // ---- MFMA + epilogue: gathers/stores use immediate offsets only ----
        #pragma unroll
        for (int nt = 0; nt < 8; ++nt) {
            f32x4 acc = {0.f, 0.f, 0.f, 0.f};
            #pragma unroll
            for (int kt = 0; kt < 4; ++kt) {
                bf16x8 bfrag = *(const bf16x8*)&w_lds[(nt * 16 + lane15) * LDK + kt * 32 + quad * 8];
                acc = __builtin_amdgcn_mfma_f32_16x16x32_bf16(afrag[kt], bfrag, acc, 0, 0, 0);
            }
            #pragma unroll
            for (int reg = 0; reg < 4; ++reg) {
                float base = cip[reg][nt * 16] + cjp[reg][nt * 16];
                float v = acc[reg] + base;
                float sv = fast_silu(v);
                if (!tail || (e0t + e_row + reg < E))
                    __builtin_nontemporal_store(sv, op[reg] + nt * 16);
            }
        }
    }
}

// ---------------------------------------------------------------------------
extern "C" void kernel_launch(void* const* d_in, const int* in_sizes, int n_in,
                              void* d_out, int out_size, void* d_ws, size_t ws_size,
                              hipStream_t stream) {
    const int*   x      = (const int*)  d_in[0];
    const int*   s      = (const int*)  d_in[1];
    const float* rbf    = (const float*)d_in[2];
    const int*   gi     = (const int*)  d_in[3];
    const int*   gj     = (const int*)  d_in[4];
    const float* emb_w  = (const float*)d_in[5];
    const float* spin_w = (const float*)d_in[6];
    const float* spin_b = (const float*)d_in[7];
    const float* rbf_w  = (const float*)d_in[8];
    const float* rbf_b  = (const float*)d_in[9];
    const float* lin_w  = (const float*)d_in[10];
    const float* lin_b  = (const float*)d_in[11];
    const int E = in_sizes[3];

    float* Ci = (float*)d_ws;                         // 285*128 f32
    float* Cj = Ci + 285 * NH;                        // 285*128 f32
    __hip_bfloat16* Wb = (__hip_bfloat16*)(Cj + 285 * NH);  // 128*128 bf16

    prep_all<<<318, 128, 0, stream>>>(emb_w, spin_w, spin_b, lin_w, lin_b, Ci, Cj, Wb);

    int ntiles = (E + TILE_E - 1) / TILE_E;
    int nblk = ntiles < NBLK ? ntiles : NBLK;
    fused_main<<<nblk, 512, 0, stream>>>(x, s, rbf, gi, gj, rbf_w, rbf_b,
                                         Ci, Cj, Wb, (float*)d_out, E, ntiles);
}